// Round 1
// baseline (129.852 us; speedup 1.0000x reference)
//
#include <hip/hip_runtime.h>
#include <hip/hip_bf16.h>
#include <math.h>

// Fused attention-gate:
//   g = BN(in_g @ Wg + bg); x = BN(in_x @ Wx + bx); s = relu(g+x)
//   psi = sigmoid(BN(s @ Wp + bp)); out = x * psi
// Strategy: fold BN into weights (pre-kernel, bf16 transposed), then one
// fused MFMA kernel: 64-pixel x 128-F tile per block, K=256 LDS-resident.

typedef __bf16 bf16x8 __attribute__((ext_vector_type(8)));
typedef float f32x4 __attribute__((ext_vector_type(4)));

__device__ __forceinline__ unsigned short f2bf(float f) {
  union { float f; unsigned u; } v; v.f = f;
  unsigned r = (v.u + 0x7fffu + ((v.u >> 16) & 1u)) >> 16;
  return (unsigned short)r;
}

// XOR-swizzled LDS byte offset for a [64][256] bf16 row-major tile.
// Breaks the stride-512B bank conflict on ds_read_b128 (16-way -> ~2-way).
__device__ __forceinline__ int lds_off(int row, int col) {
  return ((row << 9) | (col << 1)) ^ ((row & 7) << 4);
}

// ---------------- pre-kernel: fold BN into weights ----------------
__global__ __launch_bounds__(256) void fold_weights(
    const float* __restrict__ Wg, const float* __restrict__ bg,
    const float* __restrict__ gg, const float* __restrict__ beg,
    const float* __restrict__ mg, const float* __restrict__ vg,
    const float* __restrict__ Wx, const float* __restrict__ bx,
    const float* __restrict__ gx, const float* __restrict__ bex,
    const float* __restrict__ mx, const float* __restrict__ vx,
    const float* __restrict__ Wp, const float* __restrict__ bp,
    const float* __restrict__ gp, const float* __restrict__ bep,
    const float* __restrict__ mp, const float* __restrict__ vp,
    unsigned short* __restrict__ Wtg, unsigned short* __restrict__ Wtx,
    float* __restrict__ cg, float* __restrict__ cx,
    float* __restrict__ wps, float* __restrict__ cps) {
  int idx = blockIdx.x * 256 + threadIdx.x;  // 0..32767 = 256*128
  int c = idx >> 7;    // Cin index
  int f = idx & 127;   // F index
  float ivg = gg[f] * rsqrtf(vg[f] + 1e-3f);
  float ivx = gx[f] * rsqrtf(vx[f] + 1e-3f);
  // store transposed (f-major) so B-fragments are 8 contiguous k per lane
  Wtg[f * 256 + c] = f2bf(Wg[c * 128 + f] * ivg);
  Wtx[f * 256 + c] = f2bf(Wx[c * 128 + f] * ivx);
  if (idx < 128) {
    float ivg2 = gg[idx] * rsqrtf(vg[idx] + 1e-3f);
    float ivx2 = gx[idx] * rsqrtf(vx[idx] + 1e-3f);
    cg[idx] = bg[idx] * ivg2 + beg[idx] - mg[idx] * ivg2;
    cx[idx] = bx[idx] * ivx2 + bex[idx] - mx[idx] * ivx2;
    float ip = gp[0] * rsqrtf(vp[0] + 1e-3f);
    wps[idx] = Wp[idx] * ip;
    if (idx == 0) cps[0] = bp[0] * ip + bep[0] - mp[0] * ip;
  }
}

// ---------------- main fused kernel ----------------
// block = 256 threads = 4 waves in 2(M) x 2(N); tile = 64 pixels x 128 F.
__global__ __launch_bounds__(256, 2) void attn_gate_main(
    const float* __restrict__ ing, const float* __restrict__ inx,
    const unsigned short* __restrict__ Wtg, const unsigned short* __restrict__ Wtx,
    const float* __restrict__ cgp, const float* __restrict__ cxp,
    const float* __restrict__ wpp, const float* __restrict__ cpp,
    float* __restrict__ out) {
  __shared__ __align__(16) char ldsA[2 * 32768];  // A_g @0, A_x @32768 (bf16)
  __shared__ float psum[64][2];
  __shared__ float psiS[64];

  const int tid = threadIdx.x;
  const int lane = tid & 63;
  const int wid = tid >> 6;
  const int wm = wid >> 1, wn = wid & 1;
  const int l15 = lane & 15, l4 = lane >> 4;
  const long p0 = (long)blockIdx.x * 64;  // first pixel of tile

  // ---- stage both input tiles (64x256 f32 -> bf16, swizzled) ----
  for (int sel = 0; sel < 2; ++sel) {
    const float* src = sel ? inx : ing;
    const int base = sel << 15;
    #pragma unroll
    for (int it = 0; it < 8; ++it) {
      int flat = it * 2048 + tid * 8;          // f32 index in 64x256 tile
      int row = flat >> 8, col = flat & 255;   // col multiple of 8
      const float4* p = reinterpret_cast<const float4*>(src + p0 * 256 + flat);
      float4 a = p[0], b = p[1];
      union { unsigned short u[8]; int4 v; } pk;
      pk.u[0] = f2bf(a.x); pk.u[1] = f2bf(a.y);
      pk.u[2] = f2bf(a.z); pk.u[3] = f2bf(a.w);
      pk.u[4] = f2bf(b.x); pk.u[5] = f2bf(b.y);
      pk.u[6] = f2bf(b.z); pk.u[7] = f2bf(b.w);
      *reinterpret_cast<int4*>(ldsA + base + lds_off(row, col)) = pk.v;
    }
  }
  __syncthreads();

  // ---- K loop: 8 steps of 32, both GEMMs ----
  f32x4 accg[2][4] = {};
  f32x4 accx[2][4] = {};
  #pragma unroll
  for (int ks = 0; ks < 8; ++ks) {
    const int col = ks * 32 + l4 * 8;
    bf16x8 ag[2], ax[2];
    #pragma unroll
    for (int mf = 0; mf < 2; ++mf) {
      int row = wm * 32 + mf * 16 + l15;
      int off = lds_off(row, col);
      ag[mf] = *reinterpret_cast<const bf16x8*>(ldsA + off);
      ax[mf] = *reinterpret_cast<const bf16x8*>(ldsA + 32768 + off);
    }
    bf16x8 bgf[4], bxf[4];
    #pragma unroll
    for (int nf = 0; nf < 4; ++nf) {
      int f = wn * 64 + nf * 16 + l15;
      bgf[nf] = *reinterpret_cast<const bf16x8*>(Wtg + f * 256 + col);
      bxf[nf] = *reinterpret_cast<const bf16x8*>(Wtx + f * 256 + col);
    }
    #pragma unroll
    for (int mf = 0; mf < 2; ++mf)
      #pragma unroll
      for (int nf = 0; nf < 4; ++nf) {
        accg[mf][nf] = __builtin_amdgcn_mfma_f32_16x16x32_bf16(
            ag[mf], bgf[nf], accg[mf][nf], 0, 0, 0);
        accx[mf][nf] = __builtin_amdgcn_mfma_f32_16x16x32_bf16(
            ax[mf], bxf[nf], accx[mf][nf], 0, 0, 0);
      }
  }

  // ---- epilogue: bias, relu(g+x), psi dot, sigmoid, out = x*psi ----
  float cgv[4], cxv[4], wpv[4];
  #pragma unroll
  for (int nf = 0; nf < 4; ++nf) {
    int f = wn * 64 + nf * 16 + l15;
    cgv[nf] = cgp[f]; cxv[nf] = cxp[f]; wpv[nf] = wpp[f];
  }
  #pragma unroll
  for (int mf = 0; mf < 2; ++mf) {
    #pragma unroll
    for (int reg = 0; reg < 4; ++reg) {
      float part = 0.f;
      #pragma unroll
      for (int nf = 0; nf < 4; ++nf) {
        float gv = accg[mf][nf][reg] + cgv[nf];
        float xv = accx[mf][nf][reg] + cxv[nf];
        float s = gv + xv;
        s = s > 0.f ? s : 0.f;
        part += s * wpv[nf];
      }
      // reduce over the 16 lanes (l15) holding this row's 16 F-columns
      part += __shfl_xor(part, 1);
      part += __shfl_xor(part, 2);
      part += __shfl_xor(part, 4);
      part += __shfl_xor(part, 8);
      if (l15 == 0) psum[wm * 32 + mf * 16 + l4 * 4 + reg][wn] = part;
    }
  }
  __syncthreads();
  if (tid < 64) {
    float z = psum[tid][0] + psum[tid][1] + cpp[0];
    psiS[tid] = 1.f / (1.f + __expf(-z));
  }
  __syncthreads();

  #pragma unroll
  for (int mf = 0; mf < 2; ++mf)
    #pragma unroll
    for (int reg = 0; reg < 4; ++reg) {
      int r = wm * 32 + mf * 16 + l4 * 4 + reg;
      float ps = psiS[r];
      #pragma unroll
      for (int nf = 0; nf < 4; ++nf) {
        int f = wn * 64 + nf * 16 + l15;
        out[(p0 + r) * 128 + f] = (accx[mf][nf][reg] + cxv[nf]) * ps;
      }
    }
}

extern "C" void kernel_launch(void* const* d_in, const int* in_sizes, int n_in,
                              void* d_out, int out_size, void* d_ws, size_t ws_size,
                              hipStream_t stream) {
  const float* ing = (const float*)d_in[0];
  const float* inx = (const float*)d_in[1];
  char* ws = (char*)d_ws;
  unsigned short* Wtg = (unsigned short*)ws;                 // 64 KB
  unsigned short* Wtx = (unsigned short*)(ws + 65536);       // 64 KB
  float* cg  = (float*)(ws + 131072);                        // 512 B
  float* cx  = (float*)(ws + 131584);                        // 512 B
  float* wps = (float*)(ws + 132096);                        // 512 B
  float* cps = (float*)(ws + 132608);                        // 4 B

  fold_weights<<<128, 256, 0, stream>>>(
      (const float*)d_in[2],  (const float*)d_in[3],  (const float*)d_in[4],
      (const float*)d_in[5],  (const float*)d_in[6],  (const float*)d_in[7],
      (const float*)d_in[8],  (const float*)d_in[9],  (const float*)d_in[10],
      (const float*)d_in[11], (const float*)d_in[12], (const float*)d_in[13],
      (const float*)d_in[14], (const float*)d_in[15], (const float*)d_in[16],
      (const float*)d_in[17], (const float*)d_in[18], (const float*)d_in[19],
      Wtg, Wtx, cg, cx, wps, cps);

  const int npix = in_sizes[0] / 256;   // 131072
  attn_gate_main<<<npix / 64, 256, 0, stream>>>(
      ing, inx, Wtg, Wtx, cg, cx, wps, cps, (float*)d_out);
}